// Round 10
// baseline (74.892 us; speedup 1.0000x reference)
//
#include <hip/hip_runtime.h>

#define NB   8
#define CIN  32
#define HH   28
#define WW   28
#define OC   64
#define HWSZ (HH*WW)            // 784
#define TOTAL (NB*OC*HWSZ)      // 401408
#define CNT  (NB*HWSZ)          // 6272 elements per channel for BN stats

#define KH   16                 // input channels per k-half
#define TROWS 6                 // staged rows h0-1..h0+4 for 4 output rows
#define TCOLS 30
#define TSZ  (KH*TROWS*TCOLS)   // 2880 floats = 11.25 KB LDS

#define CPW  2                  // output channels per wave-pair group
// 512 threads = 8 waves: g2 = w>>1 (ch-group, 4 of CPW=2 -> 8 ch/block),
// rh = w&1 (row-half: output rows rh*2, rh*2+1).
// grid: n(8) x rowgroup(7, 4 rows each) x chgrp(8) x khalf(2) = 896 blocks,
// 7168 waves = 7/SIMD — same occupancy as the 78/74.5-us baselines, half the
// blocks, 25% less staging per output row. Inner loop identical to R0.

__global__ __launch_bounds__(512) void adder_kernel(
    const float* __restrict__ x, const float* __restrict__ Wt,
    float* __restrict__ raw01)   // raw01 = two TOTAL-sized partial buffers
{
    __shared__ float xs[TSZ];
    const int t     = threadIdx.x;
    const int bid   = blockIdx.x;
    const int khalf = bid & 1;
    const int chgrp = (bid >> 1) & 7;
    const int rg    = (bid >> 4) % 7;
    const int n     = bid / (16 * 7);
    const int h0    = rg * 4;
    const int c0    = khalf * KH;

    // ---- stage x strip: channels c0..c0+15, rows h0-1..h0+4, cols -1..28 ----
    for (int i = t; i < TSZ; i += 512) {    // 5.6 iterations
        int cc  = i / (TROWS*TCOLS);
        int rem = i % (TROWS*TCOLS);
        int r   = rem / TCOLS;
        int col = rem % TCOLS;
        int hh  = h0 - 1 + r;
        int ww  = col - 1;
        float v = 0.0f;
        if (hh >= 0 && hh < HH && ww >= 0 && ww < WW)
            v = x[((n*CIN + (c0+cc))*HH + hh)*WW + ww];
        xs[i] = v;
    }
    __syncthreads();

    const int lane  = t & 63;
    const int w     = __builtin_amdgcn_readfirstlane(t >> 6); // wave id, uniform
    const int g2    = w >> 1;                     // ch-group 0..3
    const int rh    = w & 1;                      // row-half 0..1
    const bool valid = lane < 56;                 // 2 rows x 28 cols
    const int p     = valid ? lane : 0;
    const int pr    = p / WW;                     // 0 or 1
    const int pw    = p % WW;
    const int orow  = rh*2 + pr;                  // output row in block: 0..3
    const int o_base = chgrp*8 + g2*CPW;

    float acc[CPW];
    #pragma unroll
    for (int oo = 0; oo < CPW; ++oo) acc[oo] = 0.0f;

    // current 3x3 patch in registers, prefetch next channel's patch
    // staged row index for patch row dr: orow + dr  (0..5)
    float xr[9];
    {
        int b0 = orow*TCOLS + pw;   // cc = 0
        #pragma unroll
        for (int dr = 0; dr < 3; ++dr)
            #pragma unroll
            for (int dc = 0; dc < 3; ++dc)
                xr[dr*3+dc] = xs[b0 + dr*TCOLS + dc];
    }

    for (int cc = 0; cc < KH; ++cc) {
        float xn[9];
        if (cc + 1 < KH) {
            int b2 = ((cc+1)*TROWS + orow)*TCOLS + pw;
            #pragma unroll
            for (int dr = 0; dr < 3; ++dr)
                #pragma unroll
                for (int dc = 0; dc < 3; ++dc)
                    xn[dr*3+dc] = xs[b2 + dr*TCOLS + dc];
        }
        #pragma unroll
        for (int oo = 0; oo < CPW; ++oo) {
            const float* wp = Wt + ((o_base + oo)*CIN + (c0 + cc))*9; // uniform -> s_load
            #pragma unroll
            for (int j = 0; j < 9; ++j)
                acc[oo] += __builtin_fabsf(xr[j] - wp[j]);
        }
        if (cc + 1 < KH) {
            #pragma unroll
            for (int j = 0; j < 9; ++j) xr[j] = xn[j];
        }
    }

    // ---- write negated partial sums for this k-half ----
    if (valid) {
        float* rawh = raw01 + khalf * TOTAL;
        #pragma unroll
        for (int oo = 0; oo < CPW; ++oo)
            rawh[((n*OC + o_base + oo)*HH + (h0 + orow))*WW + pw] = -acc[oo];
    }
}

// ---- merged stats + BN apply: one block per channel (unchanged from R9) ----
__global__ __launch_bounds__(256) void statsbn_kernel(
    const float* __restrict__ raw01,
    const float* __restrict__ gamma, const float* __restrict__ beta,
    float* __restrict__ out)
{
    __shared__ float vbuf[CNT];          // 6272 floats = 25 KB
    __shared__ double ls[4], ls2[4];
    __shared__ float sb[2];
    const int o = blockIdx.x;
    const int t = threadIdx.x;
    const float4* r0 = (const float4*)raw01;
    const float4* r1 = (const float4*)(raw01 + TOTAL);

    double s = 0.0, s2 = 0.0;
    #pragma unroll 2
    for (int i4 = t; i4 < CNT/4; i4 += 256) {     // 1568 float4s per channel
        int nn  = i4 / (HWSZ/4);
        int pos = i4 % (HWSZ/4);
        int idx = (nn*OC + o)*(HWSZ/4) + pos;
        float4 a = r0[idx];
        float4 b = r1[idx];
        float4 v;
        v.x = a.x + b.x; v.y = a.y + b.y; v.z = a.z + b.z; v.w = a.w + b.w;
        ((float4*)vbuf)[i4] = v;
        s  += (double)v.x + (double)v.y + (double)v.z + (double)v.w;
        s2 += (double)v.x*v.x + (double)v.y*v.y + (double)v.z*v.z + (double)v.w*v.w;
    }
    #pragma unroll
    for (int off = 32; off >= 1; off >>= 1) {
        s  += __shfl_xor(s,  off, 64);
        s2 += __shfl_xor(s2, off, 64);
    }
    const int lane = t & 63, w = t >> 6;
    if (lane == 0) { ls[w] = s; ls2[w] = s2; }
    __syncthreads();
    if (t == 0) {
        double S  = ls[0] + ls[1] + ls[2] + ls[3];
        double S2 = ls2[0] + ls2[1] + ls2[2] + ls2[3];
        double mean = S * (1.0 / CNT);
        double var  = S2 * (1.0 / CNT) - mean * mean;
        double inv  = 1.0 / sqrt(var + 1e-5);
        double scl  = (double)gamma[o] * inv;
        sb[0] = (float)scl;
        sb[1] = (float)((double)beta[o] - mean * scl);
    }
    __syncthreads();
    const float scl = sb[0], sh = sb[1];
    #pragma unroll 2
    for (int i4 = t; i4 < CNT/4; i4 += 256) {
        int nn  = i4 / (HWSZ/4);
        int pos = i4 % (HWSZ/4);
        int idx = (nn*OC + o)*(HWSZ/4) + pos;
        float4 v = ((const float4*)vbuf)[i4];
        float4 y;
        y.x = v.x * scl + sh;
        y.y = v.y * scl + sh;
        y.z = v.z * scl + sh;
        y.w = v.w * scl + sh;
        ((float4*)out)[idx] = y;
    }
}

extern "C" void kernel_launch(void* const* d_in, const int* in_sizes, int n_in,
                              void* d_out, int out_size, void* d_ws, size_t ws_size,
                              hipStream_t stream) {
    const float* x     = (const float*)d_in[0];
    const float* Wt    = (const float*)d_in[1];
    const float* gamma = (const float*)d_in[2];
    const float* beta  = (const float*)d_in[3];
    float* out = (float*)d_out;

    // ws layout: [4096, 4096+2*TOTAL*4) raw halves
    float* raw01 = (float*)((char*)d_ws + 4096);

    adder_kernel<<<NB*7*8*2, 512, 0, stream>>>(x, Wt, raw01);
    statsbn_kernel<<<OC, 256, 0, stream>>>(raw01, gamma, beta, out);
}